// Round 7
// baseline (296.699 us; speedup 1.0000x reference)
//
#include <hip/hip_runtime.h>
#include <stdint.h>

#define N_SEQ 4096
#define C_DIM 768
#define HEADS 12
#define HD    64
#define OI    (2304*768)

typedef __attribute__((ext_vector_type(8))) short short8;
typedef __attribute__((ext_vector_type(4))) float f32x4;
typedef __attribute__((ext_vector_type(16))) float f32x16;

__device__ __forceinline__ short f2bf(float f) {
  union { float f; unsigned u; } v; v.f = f;
  unsigned r = v.u + 0x7FFF + ((v.u >> 16) & 1);   // RNE
  return (short)(r >> 16);
}

// ---------------- kernel A: fused prep --------------------------------------
// blocks [0,1728): templates -> bf16 qkv_w; [1728,4800): x fp32->bf16;
// [4800,5376): proj_w fp32->bf16.
__global__ __launch_bounds__(256) void prep_all(const float* __restrict__ tmpl,
                                                const float* __restrict__ coeffs,
                                                const float* __restrict__ x,
                                                const float* __restrict__ proj_w,
                                                short* __restrict__ w_bf,
                                                short* __restrict__ x_bf,
                                                short* __restrict__ pw_bf) {
  int bid = blockIdx.x;
  if (bid < 1728) {
    __shared__ float c[16];
    if (threadIdx.x < 16)
      c[threadIdx.x] = 0.5f * (coeffs[threadIdx.x] + coeffs[16 + threadIdx.x]);
    __syncthreads();
    int idx = bid * 256 + threadIdx.x;
    int base = idx * 4;
    if (base >= OI) return;
    float ax = 0.f, ay = 0.f, az = 0.f, aw = 0.f;
#pragma unroll
    for (int t = 0; t < 16; ++t) {
      float4 v = *(const float4*)(tmpl + (size_t)t * OI + base);
      float ct = c[t];
      ax = fmaf(ct, v.x, ax); ay = fmaf(ct, v.y, ay);
      az = fmaf(ct, v.z, az); aw = fmaf(ct, v.w, aw);
    }
    short4 o = make_short4(f2bf(ax), f2bf(ay), f2bf(az), f2bf(aw));
    *(short4*)(w_bf + base) = o;
  } else if (bid < 4800) {
    int i = (bid - 1728) * 256 + threadIdx.x;   // 786432 float4 groups
    float4 v = ((const float4*)x)[i];
    ((short4*)x_bf)[i] = make_short4(f2bf(v.x), f2bf(v.y), f2bf(v.z), f2bf(v.w));
  } else {
    int i = (bid - 4800) * 256 + threadIdx.x;   // 147456 float4 groups
    if (i >= 147456) return;
    float4 v = ((const float4*)proj_w)[i];
    ((short4*)pw_bf)[i] = make_short4(f2bf(v.x), f2bf(v.y), f2bf(v.z), f2bf(v.w));
  }
}

// ---------------- kernel C: 128x128 bf16 MFMA GEMM (QKV projection) ----------
// BK=64: 12 barrier phases (was 24), 32 MFMA/phase. Double-buffered LDS,
// 2-deep reg prefetch. q pre-scaled, k plain, v TRANSPOSED [h][d][n].
#define QST 72
#define QSCALE 0.1803368801111204f   // 0.125 * log2(e)
__global__ __launch_bounds__(256) void gemm_qkv(const short* __restrict__ A,
                                                const short* __restrict__ B,
                                                const float* __restrict__ bias,
                                                short* __restrict__ qkv_out) {
  __shared__ short As[2][128 * QST];
  __shared__ short Bs[2][128 * QST];
  int tid = threadIdx.x;
  int wave = tid >> 6, lane = tid & 63, g = lane >> 4, l15 = lane & 15;
  int wm = (wave >> 1) * 64, wn = (wave & 1) * 64;
  size_t mblk = (size_t)blockIdx.x * 128;
  size_t nblk = (size_t)blockIdx.y * 128;

  f32x4 acc[4][4];
#pragma unroll
  for (int mi = 0; mi < 4; ++mi)
#pragma unroll
    for (int ni = 0; ni < 4; ++ni)
#pragma unroll
      for (int r = 0; r < 4; ++r) acc[mi][ni][r] = 0.f;

  int arow = tid >> 1;            // 0..127
  int ac   = (tid & 1) * 32;      // 0 or 32

  // prologue: k-tile0 -> regs -> buf0; k-tile1 -> regs (in flight)
  short8 ap[4], bp[4];
#pragma unroll
  for (int i = 0; i < 4; ++i) {
    ap[i] = *(const short8*)(A + (mblk + arow) * 768 + ac + 8 * i);
    bp[i] = *(const short8*)(B + (nblk + arow) * 768 + ac + 8 * i);
  }
#pragma unroll
  for (int i = 0; i < 4; ++i) {
    *(short8*)(&As[0][arow * QST + ac + 8 * i]) = ap[i];
    *(short8*)(&Bs[0][arow * QST + ac + 8 * i]) = bp[i];
  }
#pragma unroll
  for (int i = 0; i < 4; ++i) {
    ap[i] = *(const short8*)(A + (mblk + arow) * 768 + 64 + ac + 8 * i);
    bp[i] = *(const short8*)(B + (nblk + arow) * 768 + 64 + ac + 8 * i);
  }

  for (int it = 0; it < 12; ++it) {
    int cur = it & 1;
    __syncthreads();   // buf[cur] writes visible; buf[cur^1] readers done

    if (it + 1 < 12) {
#pragma unroll
      for (int i = 0; i < 4; ++i) {
        *(short8*)(&As[cur ^ 1][arow * QST + ac + 8 * i]) = ap[i];
        *(short8*)(&Bs[cur ^ 1][arow * QST + ac + 8 * i]) = bp[i];
      }
      if (it + 2 < 12) {
        int k0 = (it + 2) * 64;
#pragma unroll
        for (int i = 0; i < 4; ++i) {
          ap[i] = *(const short8*)(A + (mblk + arow) * 768 + k0 + ac + 8 * i);
          bp[i] = *(const short8*)(B + (nblk + arow) * 768 + k0 + ac + 8 * i);
        }
      }
    }

    short8 af[4][2], bfr[4][2];
#pragma unroll
    for (int mi = 0; mi < 4; ++mi)
#pragma unroll
      for (int kk = 0; kk < 2; ++kk) {
        af[mi][kk]  = *(const short8*)(&As[cur][(wm + mi * 16 + l15) * QST + kk * 32 + g * 8]);
        bfr[mi][kk] = *(const short8*)(&Bs[cur][(wn + mi * 16 + l15) * QST + kk * 32 + g * 8]);
      }
    __builtin_amdgcn_s_setprio(1);
#pragma unroll
    for (int kk = 0; kk < 2; ++kk)
#pragma unroll
      for (int mi = 0; mi < 4; ++mi)
#pragma unroll
        for (int ni = 0; ni < 4; ++ni)
          acc[mi][ni] = __builtin_amdgcn_mfma_f32_16x16x32_bf16(af[mi][kk], bfr[ni][kk], acc[mi][ni], 0, 0, 0);
    __builtin_amdgcn_s_setprio(0);
  }

#pragma unroll
  for (int ni = 0; ni < 4; ++ni) {
    int col = (int)nblk + wn + ni * 16 + l15;
    int which = col / 768;
    int rem = col - which * 768;
    int h = rem >> 6, d = rem & 63;
    float bcol = bias[col];
    if (which == 2) {
      short* vbase = qkv_out + (size_t)2 * HEADS * N_SEQ * HD
                   + ((size_t)h * HD + d) * N_SEQ;
#pragma unroll
      for (int mi = 0; mi < 4; ++mi) {
        int rowb = (int)mblk + wm + mi * 16 + g * 4;
        short4 o;
        o.x = f2bf(acc[mi][ni][0] + bcol);
        o.y = f2bf(acc[mi][ni][1] + bcol);
        o.z = f2bf(acc[mi][ni][2] + bcol);
        o.w = f2bf(acc[mi][ni][3] + bcol);
        *(short4*)(vbase + rowb) = o;
      }
    } else {
      float sc = (which == 0) ? QSCALE : 1.0f;
      short* dst = qkv_out + ((size_t)which * HEADS + h) * N_SEQ * HD + d;
#pragma unroll
      for (int mi = 0; mi < 4; ++mi) {
        int rowb = (int)mblk + wm + mi * 16 + g * 4;
#pragma unroll
        for (int r = 0; r < 4; ++r)
          dst[(size_t)(rowb + r) * HD] = f2bf((acc[mi][ni][r] + bcol) * sc);
      }
    }
  }
}

// ---------------- kernel E: 64x64 bf16 GEMM, fp32 out + bias (proj) ----------
// BK=64: 12 barrier phases, 8 MFMA/phase.
__global__ __launch_bounds__(256) void gemm_proj(const short* __restrict__ A,
                                                 const short* __restrict__ B,
                                                 const float* __restrict__ bias,
                                                 float* __restrict__ C) {
  __shared__ short As[2][64 * QST];
  __shared__ short Bs[2][64 * QST];
  int tid = threadIdx.x;
  int wave = tid >> 6, lane = tid & 63, g = lane >> 4, l15 = lane & 15;
  int wm = (wave >> 1) * 32, wn = (wave & 1) * 32;
  size_t mblk = (size_t)blockIdx.x * 64;
  size_t nblk = (size_t)blockIdx.y * 64;

  f32x4 acc[2][2];
#pragma unroll
  for (int mi = 0; mi < 2; ++mi)
#pragma unroll
    for (int ni = 0; ni < 2; ++ni)
#pragma unroll
      for (int r = 0; r < 4; ++r) acc[mi][ni][r] = 0.f;

  int prow = tid >> 2;            // 0..63
  int pc   = (tid & 3) * 16;      // 0,16,32,48

  short8 ap[2], bp[2];
#pragma unroll
  for (int i = 0; i < 2; ++i) {
    ap[i] = *(const short8*)(A + (mblk + prow) * 768 + pc + 8 * i);
    bp[i] = *(const short8*)(B + (nblk + prow) * 768 + pc + 8 * i);
  }
#pragma unroll
  for (int i = 0; i < 2; ++i) {
    *(short8*)(&As[0][prow * QST + pc + 8 * i]) = ap[i];
    *(short8*)(&Bs[0][prow * QST + pc + 8 * i]) = bp[i];
  }
#pragma unroll
  for (int i = 0; i < 2; ++i) {
    ap[i] = *(const short8*)(A + (mblk + prow) * 768 + 64 + pc + 8 * i);
    bp[i] = *(const short8*)(B + (nblk + prow) * 768 + 64 + pc + 8 * i);
  }

  for (int it = 0; it < 12; ++it) {
    int cur = it & 1;
    __syncthreads();

    if (it + 1 < 12) {
#pragma unroll
      for (int i = 0; i < 2; ++i) {
        *(short8*)(&As[cur ^ 1][prow * QST + pc + 8 * i]) = ap[i];
        *(short8*)(&Bs[cur ^ 1][prow * QST + pc + 8 * i]) = bp[i];
      }
      if (it + 2 < 12) {
        int k0 = (it + 2) * 64;
#pragma unroll
        for (int i = 0; i < 2; ++i) {
          ap[i] = *(const short8*)(A + (mblk + prow) * 768 + k0 + pc + 8 * i);
          bp[i] = *(const short8*)(B + (nblk + prow) * 768 + k0 + pc + 8 * i);
        }
      }
    }

    short8 af[2][2], bfr[2][2];
#pragma unroll
    for (int mi = 0; mi < 2; ++mi)
#pragma unroll
      for (int kk = 0; kk < 2; ++kk) {
        af[mi][kk]  = *(const short8*)(&As[cur][(wm + mi * 16 + l15) * QST + kk * 32 + g * 8]);
        bfr[mi][kk] = *(const short8*)(&Bs[cur][(wn + mi * 16 + l15) * QST + kk * 32 + g * 8]);
      }
    __builtin_amdgcn_s_setprio(1);
#pragma unroll
    for (int kk = 0; kk < 2; ++kk)
#pragma unroll
      for (int mi = 0; mi < 2; ++mi)
#pragma unroll
        for (int ni = 0; ni < 2; ++ni)
          acc[mi][ni] = __builtin_amdgcn_mfma_f32_16x16x32_bf16(af[mi][kk], bfr[ni][kk], acc[mi][ni], 0, 0, 0);
    __builtin_amdgcn_s_setprio(0);
  }

#pragma unroll
  for (int ni = 0; ni < 2; ++ni) {
    int col = (int)nblk + wn + ni * 16 + l15;
    float bcol = bias[col];
#pragma unroll
    for (int mi = 0; mi < 2; ++mi) {
      int rowb = (int)mblk + wm + mi * 16 + g * 4;
#pragma unroll
      for (int r = 0; r < 4; ++r)
        C[(size_t)(rowb + r) * 768 + col] = acc[mi][ni][r] + bcol;
    }
  }
}

// ---------------- kernel D: flash attention, 32q/wave, 4 waves/block ---------
// KVBLK=128: 16 barrier phases (was 32), 32 MFMA/phase. P in registers via
// v_cvt_pk_bf16_f32 + v_permlane32_swap_b32; K/V double-buffered in LDS.
#define KST 68     // Ks row stride (64 d + pad)
#define VST 132    // Vt row stride (128 kv + pad)
__global__ __launch_bounds__(256, 2) void attn_fa(const short* __restrict__ qkv_buf,
                                                  float* __restrict__ op0,
                                                  float* __restrict__ op1,
                                                  float* __restrict__ lp) {
  __shared__ short Ks[2][128 * KST];   // [buf][kv][d]   34,816 B
  __shared__ short Vt[2][64 * VST];    // [buf][d][kv]   33,792 B
  int bid = blockIdx.x;
  int j = (bid & 7) * 96 + (bid >> 3);    // XCD swizzle: 96 jobs/XCD
  int h = j >> 6;
  int rj = j & 63;
  int half = rj >> 5;
  int qt = rj & 31;
  int tid = threadIdx.x, wave = tid >> 6, lane = tid & 63;
  int q5 = lane & 31, h5 = lane >> 5;
  int qb = qt * 128 + wave * 32;          // wave's 32-row q base
  int kvb = half * 2048;
  const short* qh  = qkv_buf + (size_t)(0 * HEADS + h) * N_SEQ * HD;
  const short* kh  = qkv_buf + (size_t)(1 * HEADS + h) * N_SEQ * HD;
  const short* vth = qkv_buf + (size_t)2 * HEADS * N_SEQ * HD + (size_t)h * HD * N_SEQ;

  // Q B-frags from global (one-time)
  short8 qf[4];
#pragma unroll
  for (int c = 0; c < 4; ++c)
    qf[c] = *(const short8*)(qh + (size_t)(qb + q5) * HD + c * 16 + h5 * 8);

  f32x16 o_acc[2];   // [dt]
#pragma unroll
  for (int dt = 0; dt < 2; ++dt)
#pragma unroll
    for (int r = 0; r < 16; ++r) o_acc[dt][r] = 0.f;
  float l_r = 0.f;

  int krow = tid >> 1;            // 0..127
  int kc   = (tid & 1) * 32;      // 0,32
  int vrow = tid >> 2;            // 0..63
  int vq   = (tid & 3) * 32;      // 0,32,64,96

  // ---- prologue: tile0 -> regs -> buf0; tile1 -> regs (in flight) ----
  short8 kr[4], vr[4];
#pragma unroll
  for (int i = 0; i < 4; ++i) {
    kr[i] = *(const short8*)(kh + (size_t)(kvb + krow) * HD + kc + 8 * i);
    vr[i] = *(const short8*)(vth + (size_t)vrow * N_SEQ + kvb + vq + 8 * i);
  }
#pragma unroll
  for (int i = 0; i < 4; ++i) {
    *(short8*)(&Ks[0][krow * KST + kc + 8 * i]) = kr[i];
    *(short8*)(&Vt[0][vrow * VST + vq + 8 * i]) = vr[i];
  }
#pragma unroll
  for (int i = 0; i < 4; ++i) {
    kr[i] = *(const short8*)(kh + (size_t)(kvb + 128 + krow) * HD + kc + 8 * i);
    vr[i] = *(const short8*)(vth + (size_t)vrow * N_SEQ + kvb + 128 + vq + 8 * i);
  }

  for (int it = 0; it < 16; ++it) {
    int cur = it & 1;
    __syncthreads();   // buf[cur] ready; buf[cur^1] readers done

    if (it + 1 < 16) {
#pragma unroll
      for (int i = 0; i < 4; ++i) {
        *(short8*)(&Ks[cur ^ 1][krow * KST + kc + 8 * i]) = kr[i];
        *(short8*)(&Vt[cur ^ 1][vrow * VST + vq + 8 * i]) = vr[i];
      }
      if (it + 2 < 16) {
        int t2 = kvb + (it + 2) * 128;
#pragma unroll
        for (int i = 0; i < 4; ++i) {
          kr[i] = *(const short8*)(kh + (size_t)(t2 + krow) * HD + kc + 8 * i);
          vr[i] = *(const short8*)(vth + (size_t)vrow * N_SEQ + t2 + vq + 8 * i);
        }
      }
    }

    // S^T = K * Q^T : st[kt] covers kv rows kt*32..kt*32+31
    f32x16 st[4];
#pragma unroll
    for (int kt = 0; kt < 4; ++kt)
#pragma unroll
      for (int r = 0; r < 16; ++r) st[kt][r] = 0.f;
    __builtin_amdgcn_s_setprio(1);
#pragma unroll
    for (int c = 0; c < 4; ++c)
#pragma unroll
      for (int kt = 0; kt < 4; ++kt) {
        short8 kf = *(const short8*)(&Ks[cur][(kt * 32 + q5) * KST + c * 16 + h5 * 8]);
        st[kt] = __builtin_amdgcn_mfma_f32_32x32x16_bf16(kf, qf[c], st[kt], 0, 0, 0);
      }
    __builtin_amdgcn_s_setprio(0);

    // softmax in-register: p = exp2(s); PV A-frags via cvt_pk + permlane
    short8 pf[8];
#pragma unroll
    for (int kt = 0; kt < 4; ++kt)
#pragma unroll
      for (int cm = 0; cm < 2; ++cm) {
        float p0 = __builtin_amdgcn_exp2f(st[kt][cm * 8 + 0]);
        float p1 = __builtin_amdgcn_exp2f(st[kt][cm * 8 + 1]);
        float p2 = __builtin_amdgcn_exp2f(st[kt][cm * 8 + 2]);
        float p3 = __builtin_amdgcn_exp2f(st[kt][cm * 8 + 3]);
        float p4 = __builtin_amdgcn_exp2f(st[kt][cm * 8 + 4]);
        float p5 = __builtin_amdgcn_exp2f(st[kt][cm * 8 + 5]);
        float p6 = __builtin_amdgcn_exp2f(st[kt][cm * 8 + 6]);
        float p7 = __builtin_amdgcn_exp2f(st[kt][cm * 8 + 7]);
        l_r += ((p0 + p1) + (p2 + p3)) + ((p4 + p5) + (p6 + p7));
        unsigned X1, Y1, X2, Y2;
        asm("v_cvt_pk_bf16_f32 %0, %1, %2" : "=v"(X1) : "v"(p0), "v"(p1));
        asm("v_cvt_pk_bf16_f32 %0, %1, %2" : "=v"(Y1) : "v"(p4), "v"(p5));
        asm("v_cvt_pk_bf16_f32 %0, %1, %2" : "=v"(X2) : "v"(p2), "v"(p3));
        asm("v_cvt_pk_bf16_f32 %0, %1, %2" : "=v"(Y2) : "v"(p6), "v"(p7));
        asm("v_permlane32_swap_b32 %0, %1" : "+v"(X1), "+v"(Y1));
        asm("v_permlane32_swap_b32 %0, %1" : "+v"(X2), "+v"(Y2));
        union { unsigned u[4]; short8 s; } w;
        w.u[0] = X1; w.u[1] = X2; w.u[2] = Y1; w.u[3] = Y2;
        pf[kt * 2 + cm] = w.s;
      }

    // O += P V  (A = pf in regs, B = V^T frags from LDS)
    __builtin_amdgcn_s_setprio(1);
#pragma unroll
    for (int c = 0; c < 8; ++c)
#pragma unroll
      for (int dt = 0; dt < 2; ++dt) {
        short8 vf = *(const short8*)(&Vt[cur][(dt * 32 + q5) * VST + c * 16 + h5 * 8]);
        o_acc[dt] = __builtin_amdgcn_mfma_f32_32x32x16_bf16(pf[c], vf, o_acc[dt], 0, 0, 0);
      }
    __builtin_amdgcn_s_setprio(0);
  }

  float* op = half ? op1 : op0;
  float l = l_r + __shfl_xor(l_r, 32);   // combine kv-row halves
#pragma unroll
  for (int cc = 0; cc < 4; ++cc)
#pragma unroll
    for (int rr = 0; rr < 4; ++rr) {
      int qloc = rr + 8 * cc + 4 * h5;
      size_t base = ((size_t)h * N_SEQ + qb + qloc) * HD;
#pragma unroll
      for (int dt = 0; dt < 2; ++dt)
        op[base + dt * 32 + q5] = o_acc[dt][cc * 4 + rr];
    }
  if (h5 == 0)
    lp[((size_t)half * HEADS + h) * N_SEQ + qb + q5] = l;
}

// ---------------- kernel D2: combine kv-split partials -> bf16 [n][c] --------
__global__ __launch_bounds__(256) void attn_reduce(const float* __restrict__ op0,
                                                   const float* __restrict__ op1,
                                                   const float* __restrict__ lp,
                                                   short* __restrict__ out_bf) {
  int idx = blockIdx.x * 256 + threadIdx.x;   // [12][4096][16]
  int d4 = idx & 15;
  int n  = (idx >> 4) & 4095;
  int h  = idx >> 16;
  size_t o = ((size_t)h * N_SEQ + n) * HD + d4 * 4;
  float4 a = *(const float4*)(op0 + o);
  float4 b = *(const float4*)(op1 + o);
  float l = lp[(size_t)h * N_SEQ + n] + lp[((size_t)HEADS + h) * N_SEQ + n];
  float inv = 1.0f / l;
  short4 s = make_short4(f2bf((a.x + b.x) * inv), f2bf((a.y + b.y) * inv),
                         f2bf((a.z + b.z) * inv), f2bf((a.w + b.w) * inv));
  *(short4*)(out_bf + (size_t)n * C_DIM + h * HD + d4 * 4) = s;
}

// ---------------- launcher ---------------------------------------------------
extern "C" void kernel_launch(void* const* d_in, const int* in_sizes, int n_in,
                              void* d_out, int out_size, void* d_ws, size_t ws_size,
                              hipStream_t stream) {
  const float* x        = (const float*)d_in[0];
  const float* tmpl     = (const float*)d_in[1];
  const float* coeffs   = (const float*)d_in[2];
  const float* qkv_bias = (const float*)d_in[3];
  const float* proj_w   = (const float*)d_in[4];
  const float* proj_b   = (const float*)d_in[5];
  float* out = (float*)d_out;
  char* ws = (char*)d_ws;

  short* w_bf    = (short*)(ws);                 // 2304*768
  short* x_bf    = (short*)(ws + 3538944);       // 4096*768
  short* pw_bf   = (short*)(ws + 9830400);       // 768*768
  short* qkvb    = (short*)(ws + 11010048);      // 3*12*4096*64 (v transposed)
  short* attn_bf = (short*)(ws + 29884416);      // 4096*768 bf16
  float* opart1  = (float*)(ws + 36175872);      // [12][4096][64] fp32 (12.58 MB)
  float* lpart   = (float*)(ws + 48758784);      // [2][12][4096] fp32 (0.39 MB)
  float* opart0  = out;                          // d_out reused (dead until proj)

  prep_all<<<5376, 256, 0, stream>>>(tmpl, coeffs, x, proj_w, w_bf, x_bf, pw_bf);

  dim3 g1(32, 18);
  gemm_qkv<<<g1, 256, 0, stream>>>(x_bf, w_bf, qkv_bias, qkvb);

  attn_fa<<<768, 256, 0, stream>>>(qkvb, opart0, opart1, lpart);
  attn_reduce<<<3072, 256, 0, stream>>>(opart0, opart1, lpart, attn_bf);

  dim3 g2(64, 12);
  gemm_proj<<<g2, 256, 0, stream>>>(attn_bf, pw_bf, proj_b, out);
}

// Round 8
// 290.131 us; speedup vs baseline: 1.0226x; 1.0226x over previous
//
#include <hip/hip_runtime.h>
#include <stdint.h>

#define N_SEQ 4096
#define C_DIM 768
#define HEADS 12
#define HD    64
#define OI    (2304*768)

typedef __attribute__((ext_vector_type(8))) short short8;
typedef __attribute__((ext_vector_type(4))) float f32x4;
typedef __attribute__((ext_vector_type(16))) float f32x16;

__device__ __forceinline__ short f2bf(float f) {
  union { float f; unsigned u; } v; v.f = f;
  unsigned r = v.u + 0x7FFF + ((v.u >> 16) & 1);   // RNE
  return (short)(r >> 16);
}

// ---------------- kernel A: fused prep --------------------------------------
// blocks [0,1728): templates -> bf16 qkv_w; [1728,4800): x fp32->bf16;
// [4800,5376): proj_w fp32->bf16.
__global__ __launch_bounds__(256) void prep_all(const float* __restrict__ tmpl,
                                                const float* __restrict__ coeffs,
                                                const float* __restrict__ x,
                                                const float* __restrict__ proj_w,
                                                short* __restrict__ w_bf,
                                                short* __restrict__ x_bf,
                                                short* __restrict__ pw_bf) {
  int bid = blockIdx.x;
  if (bid < 1728) {
    __shared__ float c[16];
    if (threadIdx.x < 16)
      c[threadIdx.x] = 0.5f * (coeffs[threadIdx.x] + coeffs[16 + threadIdx.x]);
    __syncthreads();
    int idx = bid * 256 + threadIdx.x;
    int base = idx * 4;
    if (base >= OI) return;
    float ax = 0.f, ay = 0.f, az = 0.f, aw = 0.f;
#pragma unroll
    for (int t = 0; t < 16; ++t) {
      float4 v = *(const float4*)(tmpl + (size_t)t * OI + base);
      float ct = c[t];
      ax = fmaf(ct, v.x, ax); ay = fmaf(ct, v.y, ay);
      az = fmaf(ct, v.z, az); aw = fmaf(ct, v.w, aw);
    }
    short4 o = make_short4(f2bf(ax), f2bf(ay), f2bf(az), f2bf(aw));
    *(short4*)(w_bf + base) = o;
  } else if (bid < 4800) {
    int i = (bid - 1728) * 256 + threadIdx.x;   // 786432 float4 groups
    float4 v = ((const float4*)x)[i];
    ((short4*)x_bf)[i] = make_short4(f2bf(v.x), f2bf(v.y), f2bf(v.z), f2bf(v.w));
  } else {
    int i = (bid - 4800) * 256 + threadIdx.x;   // 147456 float4 groups
    if (i >= 147456) return;
    float4 v = ((const float4*)proj_w)[i];
    ((short4*)pw_bf)[i] = make_short4(f2bf(v.x), f2bf(v.y), f2bf(v.z), f2bf(v.w));
  }
}

// ---------------- kernel C: 128x128 bf16 MFMA GEMM (QKV projection) ----------
// BK=64: 12 barrier phases, 32 MFMA/phase. Double-buffered LDS, 2-deep reg
// prefetch. q pre-scaled, k plain, v TRANSPOSED [h][d][n].  (round-7, kept)
#define QST 72
#define QSCALE 0.1803368801111204f   // 0.125 * log2(e)
__global__ __launch_bounds__(256) void gemm_qkv(const short* __restrict__ A,
                                                const short* __restrict__ B,
                                                const float* __restrict__ bias,
                                                short* __restrict__ qkv_out) {
  __shared__ short As[2][128 * QST];
  __shared__ short Bs[2][128 * QST];
  int tid = threadIdx.x;
  int wave = tid >> 6, lane = tid & 63, g = lane >> 4, l15 = lane & 15;
  int wm = (wave >> 1) * 64, wn = (wave & 1) * 64;
  size_t mblk = (size_t)blockIdx.x * 128;
  size_t nblk = (size_t)blockIdx.y * 128;

  f32x4 acc[4][4];
#pragma unroll
  for (int mi = 0; mi < 4; ++mi)
#pragma unroll
    for (int ni = 0; ni < 4; ++ni)
#pragma unroll
      for (int r = 0; r < 4; ++r) acc[mi][ni][r] = 0.f;

  int arow = tid >> 1;            // 0..127
  int ac   = (tid & 1) * 32;      // 0 or 32

  // prologue: k-tile0 -> regs -> buf0; k-tile1 -> regs (in flight)
  short8 ap[4], bp[4];
#pragma unroll
  for (int i = 0; i < 4; ++i) {
    ap[i] = *(const short8*)(A + (mblk + arow) * 768 + ac + 8 * i);
    bp[i] = *(const short8*)(B + (nblk + arow) * 768 + ac + 8 * i);
  }
#pragma unroll
  for (int i = 0; i < 4; ++i) {
    *(short8*)(&As[0][arow * QST + ac + 8 * i]) = ap[i];
    *(short8*)(&Bs[0][arow * QST + ac + 8 * i]) = bp[i];
  }
#pragma unroll
  for (int i = 0; i < 4; ++i) {
    ap[i] = *(const short8*)(A + (mblk + arow) * 768 + 64 + ac + 8 * i);
    bp[i] = *(const short8*)(B + (nblk + arow) * 768 + 64 + ac + 8 * i);
  }

  for (int it = 0; it < 12; ++it) {
    int cur = it & 1;
    __syncthreads();   // buf[cur] writes visible; buf[cur^1] readers done

    if (it + 1 < 12) {
#pragma unroll
      for (int i = 0; i < 4; ++i) {
        *(short8*)(&As[cur ^ 1][arow * QST + ac + 8 * i]) = ap[i];
        *(short8*)(&Bs[cur ^ 1][arow * QST + ac + 8 * i]) = bp[i];
      }
      if (it + 2 < 12) {
        int k0 = (it + 2) * 64;
#pragma unroll
        for (int i = 0; i < 4; ++i) {
          ap[i] = *(const short8*)(A + (mblk + arow) * 768 + k0 + ac + 8 * i);
          bp[i] = *(const short8*)(B + (nblk + arow) * 768 + k0 + ac + 8 * i);
        }
      }
    }

    short8 af[4][2], bfr[4][2];
#pragma unroll
    for (int mi = 0; mi < 4; ++mi)
#pragma unroll
      for (int kk = 0; kk < 2; ++kk) {
        af[mi][kk]  = *(const short8*)(&As[cur][(wm + mi * 16 + l15) * QST + kk * 32 + g * 8]);
        bfr[mi][kk] = *(const short8*)(&Bs[cur][(wn + mi * 16 + l15) * QST + kk * 32 + g * 8]);
      }
    __builtin_amdgcn_s_setprio(1);
#pragma unroll
    for (int kk = 0; kk < 2; ++kk)
#pragma unroll
      for (int mi = 0; mi < 4; ++mi)
#pragma unroll
        for (int ni = 0; ni < 4; ++ni)
          acc[mi][ni] = __builtin_amdgcn_mfma_f32_16x16x32_bf16(af[mi][kk], bfr[ni][kk], acc[mi][ni], 0, 0, 0);
    __builtin_amdgcn_s_setprio(0);
  }

#pragma unroll
  for (int ni = 0; ni < 4; ++ni) {
    int col = (int)nblk + wn + ni * 16 + l15;
    int which = col / 768;
    int rem = col - which * 768;
    int h = rem >> 6, d = rem & 63;
    float bcol = bias[col];
    if (which == 2) {
      short* vbase = qkv_out + (size_t)2 * HEADS * N_SEQ * HD
                   + ((size_t)h * HD + d) * N_SEQ;
#pragma unroll
      for (int mi = 0; mi < 4; ++mi) {
        int rowb = (int)mblk + wm + mi * 16 + g * 4;
        short4 o;
        o.x = f2bf(acc[mi][ni][0] + bcol);
        o.y = f2bf(acc[mi][ni][1] + bcol);
        o.z = f2bf(acc[mi][ni][2] + bcol);
        o.w = f2bf(acc[mi][ni][3] + bcol);
        *(short4*)(vbase + rowb) = o;
      }
    } else {
      float sc = (which == 0) ? QSCALE : 1.0f;
      short* dst = qkv_out + ((size_t)which * HEADS + h) * N_SEQ * HD + d;
#pragma unroll
      for (int mi = 0; mi < 4; ++mi) {
        int rowb = (int)mblk + wm + mi * 16 + g * 4;
#pragma unroll
        for (int r = 0; r < 4; ++r)
          dst[(size_t)(rowb + r) * HD] = f2bf((acc[mi][ni][r] + bcol) * sc);
      }
    }
  }
}

// ---------------- kernel E: 64x64 bf16 GEMM, fp32 out + bias (proj) ----------
// BK=64: 12 barrier phases, 8 MFMA/phase. (round-7, kept)
__global__ __launch_bounds__(256) void gemm_proj(const short* __restrict__ A,
                                                 const short* __restrict__ B,
                                                 const float* __restrict__ bias,
                                                 float* __restrict__ C) {
  __shared__ short As[2][64 * QST];
  __shared__ short Bs[2][64 * QST];
  int tid = threadIdx.x;
  int wave = tid >> 6, lane = tid & 63, g = lane >> 4, l15 = lane & 15;
  int wm = (wave >> 1) * 32, wn = (wave & 1) * 32;
  size_t mblk = (size_t)blockIdx.x * 64;
  size_t nblk = (size_t)blockIdx.y * 64;

  f32x4 acc[2][2];
#pragma unroll
  for (int mi = 0; mi < 2; ++mi)
#pragma unroll
    for (int ni = 0; ni < 2; ++ni)
#pragma unroll
      for (int r = 0; r < 4; ++r) acc[mi][ni][r] = 0.f;

  int prow = tid >> 2;            // 0..63
  int pc   = (tid & 3) * 16;      // 0,16,32,48

  short8 ap[2], bp[2];
#pragma unroll
  for (int i = 0; i < 2; ++i) {
    ap[i] = *(const short8*)(A + (mblk + prow) * 768 + pc + 8 * i);
    bp[i] = *(const short8*)(B + (nblk + prow) * 768 + pc + 8 * i);
  }
#pragma unroll
  for (int i = 0; i < 2; ++i) {
    *(short8*)(&As[0][prow * QST + pc + 8 * i]) = ap[i];
    *(short8*)(&Bs[0][prow * QST + pc + 8 * i]) = bp[i];
  }
#pragma unroll
  for (int i = 0; i < 2; ++i) {
    ap[i] = *(const short8*)(A + (mblk + prow) * 768 + 64 + pc + 8 * i);
    bp[i] = *(const short8*)(B + (nblk + prow) * 768 + 64 + pc + 8 * i);
  }

  for (int it = 0; it < 12; ++it) {
    int cur = it & 1;
    __syncthreads();

    if (it + 1 < 12) {
#pragma unroll
      for (int i = 0; i < 2; ++i) {
        *(short8*)(&As[cur ^ 1][prow * QST + pc + 8 * i]) = ap[i];
        *(short8*)(&Bs[cur ^ 1][prow * QST + pc + 8 * i]) = bp[i];
      }
      if (it + 2 < 12) {
        int k0 = (it + 2) * 64;
#pragma unroll
        for (int i = 0; i < 2; ++i) {
          ap[i] = *(const short8*)(A + (mblk + prow) * 768 + k0 + pc + 8 * i);
          bp[i] = *(const short8*)(B + (nblk + prow) * 768 + k0 + pc + 8 * i);
        }
      }
    }

    short8 af[2][2], bfr[2][2];
#pragma unroll
    for (int mi = 0; mi < 2; ++mi)
#pragma unroll
      for (int kk = 0; kk < 2; ++kk) {
        af[mi][kk]  = *(const short8*)(&As[cur][(wm + mi * 16 + l15) * QST + kk * 32 + g * 8]);
        bfr[mi][kk] = *(const short8*)(&Bs[cur][(wn + mi * 16 + l15) * QST + kk * 32 + g * 8]);
      }
    __builtin_amdgcn_s_setprio(1);
#pragma unroll
    for (int kk = 0; kk < 2; ++kk)
#pragma unroll
      for (int mi = 0; mi < 2; ++mi)
#pragma unroll
        for (int ni = 0; ni < 2; ++ni)
          acc[mi][ni] = __builtin_amdgcn_mfma_f32_16x16x32_bf16(af[mi][kk], bfr[ni][kk], acc[mi][ni], 0, 0, 0);
    __builtin_amdgcn_s_setprio(0);
  }

#pragma unroll
  for (int ni = 0; ni < 2; ++ni) {
    int col = (int)nblk + wn + ni * 16 + l15;
    float bcol = bias[col];
#pragma unroll
    for (int mi = 0; mi < 2; ++mi) {
      int rowb = (int)mblk + wm + mi * 16 + g * 4;
#pragma unroll
      for (int r = 0; r < 4; ++r)
        C[(size_t)(rowb + r) * 768 + col] = acc[mi][ni][r] + bcol;
    }
  }
}

// ---------------- kernel D: flash attention, 32q/wave, 4 waves/block ---------
// ROUND-6 VERSION (verified 67.6us, 0 bank conflicts): KVBLK=64, P in
// registers via v_cvt_pk_bf16_f32 + v_permlane32_swap_b32; K/V double-
// buffered in LDS -> ONE __syncthreads per kv-tile; setprio around MFMA.
#define PST 68
__global__ __launch_bounds__(256, 2) void attn_fa(const short* __restrict__ qkv_buf,
                                                  float* __restrict__ op0,
                                                  float* __restrict__ op1,
                                                  float* __restrict__ lp) {
  __shared__ short Ks[2][64 * PST];    // [buf][kv][d]
  __shared__ short Vt[2][64 * PST];    // [buf][d][kv]
  int bid = blockIdx.x;
  int j = (bid & 7) * 96 + (bid >> 3);    // XCD swizzle: 96 jobs/XCD, heads clustered
  int h = j >> 6;
  int rj = j & 63;
  int half = rj >> 5;
  int qt = rj & 31;
  int tid = threadIdx.x, wave = tid >> 6, lane = tid & 63;
  int q5 = lane & 31, h5 = lane >> 5;
  int qb = qt * 128 + wave * 32;          // wave's 32-row q base
  int kvb = half * 2048;
  const short* qh  = qkv_buf + (size_t)(0 * HEADS + h) * N_SEQ * HD;
  const short* kh  = qkv_buf + (size_t)(1 * HEADS + h) * N_SEQ * HD;
  const short* vth = qkv_buf + (size_t)2 * HEADS * N_SEQ * HD + (size_t)h * HD * N_SEQ;

  // Q B-frags from global (one-time): n=q5, k=h5*8+j (+16c)
  short8 qf[4];
#pragma unroll
  for (int c = 0; c < 4; ++c)
    qf[c] = *(const short8*)(qh + (size_t)(qb + q5) * HD + c * 16 + h5 * 8);

  f32x16 o_acc[2];   // [dt]
#pragma unroll
  for (int dt = 0; dt < 2; ++dt)
#pragma unroll
    for (int r = 0; r < 16; ++r) o_acc[dt][r] = 0.f;
  float l_r = 0.f;

  int srow = tid >> 2;            // 0..63
  int sq   = (tid & 3) * 16;

  // ---- prologue: tile0 -> regs -> buf0; tile1 -> regs (in flight) ----
  short8 kr[2], vr[2];
#pragma unroll
  for (int i = 0; i < 2; ++i) {
    kr[i] = *(const short8*)(kh + (size_t)(kvb + srow) * HD + sq + 8 * i);
    vr[i] = *(const short8*)(vth + (size_t)srow * N_SEQ + kvb + sq + 8 * i);
  }
#pragma unroll
  for (int i = 0; i < 2; ++i) {
    *(short8*)(&Ks[0][srow * PST + sq + 8 * i]) = kr[i];
    *(short8*)(&Vt[0][srow * PST + sq + 8 * i]) = vr[i];
  }
#pragma unroll
  for (int i = 0; i < 2; ++i) {
    kr[i] = *(const short8*)(kh + (size_t)(kvb + 64 + srow) * HD + sq + 8 * i);
    vr[i] = *(const short8*)(vth + (size_t)srow * N_SEQ + kvb + 64 + sq + 8 * i);
  }

  for (int it = 0; it < 32; ++it) {
    int cur = it & 1;
    // single barrier per tile: buf[cur] writes visible; buf[cur^1] readers done
    __syncthreads();

    if (it + 1 < 32) {
      // write prefetched tile it+1 into the other buffer
#pragma unroll
      for (int i = 0; i < 2; ++i) {
        *(short8*)(&Ks[cur ^ 1][srow * PST + sq + 8 * i]) = kr[i];
        *(short8*)(&Vt[cur ^ 1][srow * PST + sq + 8 * i]) = vr[i];
      }
      if (it + 2 < 32) {
        int t2 = kvb + (it + 2) * 64;
#pragma unroll
        for (int i = 0; i < 2; ++i) {
          kr[i] = *(const short8*)(kh + (size_t)(t2 + srow) * HD + sq + 8 * i);
          vr[i] = *(const short8*)(vth + (size_t)srow * N_SEQ + t2 + sq + 8 * i);
        }
      }
    }

    // S^T = K * Q^T  (rows = k via crow(r,h5), cols = q = q5)
    f32x16 st[2];    // [kt]
#pragma unroll
    for (int kt = 0; kt < 2; ++kt)
#pragma unroll
      for (int r = 0; r < 16; ++r) st[kt][r] = 0.f;
    __builtin_amdgcn_s_setprio(1);
#pragma unroll
    for (int c = 0; c < 4; ++c)
#pragma unroll
      for (int kt = 0; kt < 2; ++kt) {
        short8 kf = *(const short8*)(&Ks[cur][(kt * 32 + q5) * PST + c * 16 + h5 * 8]);
        st[kt] = __builtin_amdgcn_mfma_f32_32x32x16_bf16(kf, qf[c], st[kt], 0, 0, 0);
      }
    __builtin_amdgcn_s_setprio(0);

    // softmax in-register: p = exp2(s); build PV A-frags via cvt_pk + permlane
    short8 pf[4];
#pragma unroll
    for (int kt = 0; kt < 2; ++kt)
#pragma unroll
      for (int cm = 0; cm < 2; ++cm) {
        float p0 = __builtin_amdgcn_exp2f(st[kt][cm * 8 + 0]);
        float p1 = __builtin_amdgcn_exp2f(st[kt][cm * 8 + 1]);
        float p2 = __builtin_amdgcn_exp2f(st[kt][cm * 8 + 2]);
        float p3 = __builtin_amdgcn_exp2f(st[kt][cm * 8 + 3]);
        float p4 = __builtin_amdgcn_exp2f(st[kt][cm * 8 + 4]);
        float p5 = __builtin_amdgcn_exp2f(st[kt][cm * 8 + 5]);
        float p6 = __builtin_amdgcn_exp2f(st[kt][cm * 8 + 6]);
        float p7 = __builtin_amdgcn_exp2f(st[kt][cm * 8 + 7]);
        l_r += ((p0 + p1) + (p2 + p3)) + ((p4 + p5) + (p6 + p7));
        unsigned X1, Y1, X2, Y2;
        asm("v_cvt_pk_bf16_f32 %0, %1, %2" : "=v"(X1) : "v"(p0), "v"(p1));
        asm("v_cvt_pk_bf16_f32 %0, %1, %2" : "=v"(Y1) : "v"(p4), "v"(p5));
        asm("v_cvt_pk_bf16_f32 %0, %1, %2" : "=v"(X2) : "v"(p2), "v"(p3));
        asm("v_cvt_pk_bf16_f32 %0, %1, %2" : "=v"(Y2) : "v"(p6), "v"(p7));
        // swap X.hi-lanes <-> Y.lo-lanes: X'=W0/W1, Y'=W2/W3 for both halves
        asm("v_permlane32_swap_b32 %0, %1" : "+v"(X1), "+v"(Y1));
        asm("v_permlane32_swap_b32 %0, %1" : "+v"(X2), "+v"(Y2));
        union { unsigned u[4]; short8 s; } w;
        w.u[0] = X1; w.u[1] = X2; w.u[2] = Y1; w.u[3] = Y2;
        pf[kt * 2 + cm] = w.s;
      }

    // O += P V  (A = pf in regs, B = V^T frags from LDS)
    __builtin_amdgcn_s_setprio(1);
#pragma unroll
    for (int c = 0; c < 4; ++c)
#pragma unroll
      for (int dt = 0; dt < 2; ++dt) {
        short8 vf = *(const short8*)(&Vt[cur][(dt * 32 + q5) * PST + c * 16 + h5 * 8]);
        o_acc[dt] = __builtin_amdgcn_mfma_f32_32x32x16_bf16(pf[c], vf, o_acc[dt], 0, 0, 0);
      }
    __builtin_amdgcn_s_setprio(0);
  }

  float* op = half ? op1 : op0;
  float l = l_r + __shfl_xor(l_r, 32);   // combine kv-row halves
#pragma unroll
  for (int cc = 0; cc < 4; ++cc)
#pragma unroll
    for (int rr = 0; rr < 4; ++rr) {
      int qloc = rr + 8 * cc + 4 * h5;
      size_t base = ((size_t)h * N_SEQ + qb + qloc) * HD;
#pragma unroll
      for (int dt = 0; dt < 2; ++dt)
        op[base + dt * 32 + q5] = o_acc[dt][cc * 4 + rr];
    }
  if (h5 == 0)
    lp[((size_t)half * HEADS + h) * N_SEQ + qb + q5] = l;
}

// ---------------- kernel D2: combine kv-split partials -> bf16 [n][c] --------
__global__ __launch_bounds__(256) void attn_reduce(const float* __restrict__ op0,
                                                   const float* __restrict__ op1,
                                                   const float* __restrict__ lp,
                                                   short* __restrict__ out_bf) {
  int idx = blockIdx.x * 256 + threadIdx.x;   // [12][4096][16]
  int d4 = idx & 15;
  int n  = (idx >> 4) & 4095;
  int h  = idx >> 16;
  size_t o = ((size_t)h * N_SEQ + n) * HD + d4 * 4;
  float4 a = *(const float4*)(op0 + o);
  float4 b = *(const float4*)(op1 + o);
  float l = lp[(size_t)h * N_SEQ + n] + lp[((size_t)HEADS + h) * N_SEQ + n];
  float inv = 1.0f / l;
  short4 s = make_short4(f2bf((a.x + b.x) * inv), f2bf((a.y + b.y) * inv),
                         f2bf((a.z + b.z) * inv), f2bf((a.w + b.w) * inv));
  *(short4*)(out_bf + (size_t)n * C_DIM + h * HD + d4 * 4) = s;
}

// ---------------- launcher ---------------------------------------------------
extern "C" void kernel_launch(void* const* d_in, const int* in_sizes, int n_in,
                              void* d_out, int out_size, void* d_ws, size_t ws_size,
                              hipStream_t stream) {
  const float* x        = (const float*)d_in[0];
  const float* tmpl     = (const float*)d_in[1];
  const float* coeffs   = (const float*)d_in[2];
  const float* qkv_bias = (const float*)d_in[3];
  const float* proj_w   = (const float*)d_in[4];
  const float* proj_b   = (const float*)d_in[5];
  float* out = (float*)d_out;
  char* ws = (char*)d_ws;

  short* w_bf    = (short*)(ws);                 // 2304*768
  short* x_bf    = (short*)(ws + 3538944);       // 4096*768
  short* pw_bf   = (short*)(ws + 9830400);       // 768*768
  short* qkvb    = (short*)(ws + 11010048);      // 3*12*4096*64 (v transposed)
  short* attn_bf = (short*)(ws + 29884416);      // 4096*768 bf16
  float* opart1  = (float*)(ws + 36175872);      // [12][4096][64] fp32 (12.58 MB)
  float* lpart   = (float*)(ws + 48758784);      // [2][12][4096] fp32 (0.39 MB)
  float* opart0  = out;                          // d_out reused (dead until proj)

  prep_all<<<5376, 256, 0, stream>>>(tmpl, coeffs, x, proj_w, w_bf, x_bf, pw_bf);

  dim3 g1(32, 18);
  gemm_qkv<<<g1, 256, 0, stream>>>(x_bf, w_bf, qkv_bias, qkvb);

  attn_fa<<<768, 256, 0, stream>>>(qkvb, opart0, opart1, lpart);
  attn_reduce<<<3072, 256, 0, stream>>>(opart0, opart1, lpart, attn_bf);

  dim3 g2(64, 12);
  gemm_proj<<<g2, 256, 0, stream>>>(attn_bf, pw_bf, proj_b, out);
}